// Round 20
// baseline (133.939 us; speedup 1.0000x reference)
//
#include <hip/hip_runtime.h>
#include <hip/hip_fp16.h>

// ---------------------------------------------------------------------------
// GATv2 (2 layers): scatter -> per-bucket dst-sort -> wave-per-node gathers.
// Bucket = dst >> 6 (64 nodes/bucket, 782 buckets).
//  1) bucket_scatter: block counting sort -> bucket-grouped global buf.
//     CHUNK=4096 (R19 lesson: at CHUNK=8192 only 196 of 512 co-resident
//     block slots were filled -- 38% machine fill; 4096 -> 391 blocks/76%).
//  2) sortbuf: per bucket, sort entries by dst, write u16 src lists +
//     per-node (beg,cnt) descriptors. SELF-LOOP APPENDED to each node's
//     segment (scan over hist+1) -- gathers have no separate self pass.
//  3) gather1w: ONE WAVE PER NODE, head-per-lane (lane = eslot*8+h; lane
//     holds all 8 fp16 channels of head h as uint4; 8 edges per pass,
//     one coalesced u16 chunk per 64 edges + shfl broadcast of ids).
//     Inner loop = STATIC 2x4-pass groups: 4 gathers issued back-to-back
//     (R18 lesson: dynamic kn predication broke load clustering; R16
//     lesson: scalar broadcast loads serialize VMEM latency).
//     f16 math via __builtin_elementwise_* (R15 lesson: .x/.y scalar
//     selects scalarize to ~4x VALU fat).
//  4) gather2w: one wave per node, scalar layer-2 features (self in list).
// bcnt zeroing folded into the gemm launch (tail blocks) -- no memset.
// No fp atomics in hot paths (R8/R9). Softmax without max-subtraction
// (scores O(10), fp32-safe; shift-invariant).
// ---------------------------------------------------------------------------

#define NEG_SLOPE 0.2f
#define LOG2E 1.4426950408889634f
#define CB_SHIFT 6
#define CB_MASK 63
#define CAP_C 3072     // mean 2048/bucket; clamp to CAP_C-64 to fit selfs
#define CHUNK 4096     // edges per scatter block (4 per thread; 391 blocks)
#define CNT_STRIDE 32  // one counter per 128B

#if __has_builtin(__builtin_amdgcn_exp2f)
#define EXP2(x) __builtin_amdgcn_exp2f(x)
#else
#define EXP2(x) __expf((x)*0.6931471805599453f)
#endif

typedef _Float16 h2 __attribute__((ext_vector_type(2)));

__device__ __forceinline__ h2 lrelu_pk(h2 t, h2 slope) {
  return __builtin_elementwise_max(t, t * slope);  // v_pk_mul + v_pk_max
}

// Dual GEMM, split grid: blocks [0,half) -> xlh, [half,2*half) -> xrh (fp16).
// Blocks [2*half, 2*half+ZB) zero bcnt (replaces hipMemsetAsync launch).
__global__ __launch_bounds__(256) void gemm_reg_dual(
    const float* __restrict__ x, const float* __restrict__ Wl,
    const float* __restrict__ Wr, __half* __restrict__ xlh,
    __half* __restrict__ xrh, int N, int half_blocks,
    int* __restrict__ bcnt, int bcnt_n) {
  if ((int)blockIdx.x >= 2 * half_blocks) {
    int zb = blockIdx.x - 2 * half_blocks;
    for (int i = zb * 256 + threadIdx.x; i < bcnt_n; i += 256 * 16)
      bcnt[i] = 0;
    return;
  }
  bool second = blockIdx.x >= half_blocks;
  int bid = second ? blockIdx.x - half_blocks : blockIdx.x;
  const float* __restrict__ W = second ? Wr : Wl;
  __half* __restrict__ dst = second ? xrh : xlh;
  int nwaves = half_blocks * 4;
  int wid = bid * 4 + (threadIdx.x >> 6);
  int j = threadIdx.x & 63;
  float Wcol[128];
#pragma unroll
  for (int k = 0; k < 128; ++k) Wcol[k] = W[k * 64 + j];  // coalesced, L2-hot
  for (int n = wid; n < N; n += nwaves) {
    const float2 xv2 = *(const float2*)&x[(size_t)n * 128 + 2 * j];
    float xa = xv2.x, xb = xv2.y;
    float acc0 = 0.f, acc1 = 0.f;
#pragma unroll
    for (int k = 0; k < 128; k += 2) {
      unsigned b0 = __builtin_amdgcn_readlane(__float_as_uint(xa), k >> 1);
      unsigned b1 = __builtin_amdgcn_readlane(__float_as_uint(xb), k >> 1);
      acc0 = fmaf(__uint_as_float(b0), Wcol[k], acc0);
      acc1 = fmaf(__uint_as_float(b1), Wcol[k + 1], acc1);
    }
    dst[(size_t)n * 64 + j] = __float2half(acc0 + acc1);
  }
}

// Block-level counting-sort scatter: CHUNK edges -> bucket-grouped global buf.
__global__ __launch_bounds__(1024) void bucket_scatter(
    const int* __restrict__ ei, int E0, int* __restrict__ bcnt,
    int* __restrict__ buf) {
  __shared__ int hist[1024];
  __shared__ int sc[1024];
  __shared__ int gofs[1024];
  __shared__ int wpart[16];
  __shared__ unsigned stage[CHUNK];
  int tid = threadIdx.x;
  int lane = tid & 63, wv = tid >> 6;
  int base = blockIdx.x * CHUNK;
  hist[tid] = 0;
  __syncthreads();
  int bb[4], pp[4], ent[4];
#pragma unroll
  for (int r = 0; r < 4; ++r) {
    int e = base + r * 1024 + tid;
    if (e < E0) {
      int s = ei[e], d = ei[E0 + e];
      int b = d >> CB_SHIFT;
      bb[r] = b;
      ent[r] = (s << CB_SHIFT) | (d & CB_MASK);
      pp[r] = atomicAdd(&hist[b], 1);
    } else {
      bb[r] = -1;
    }
  }
  __syncthreads();
  int v = hist[tid];
  int inc = v;
#pragma unroll
  for (int off = 1; off < 64; off <<= 1) {
    int u = __shfl_up(inc, off);
    if (lane >= off) inc += u;
  }
  if (lane == 63) wpart[wv] = inc;
  __syncthreads();
  if (tid < 16) {
    int is = wpart[tid];
#pragma unroll
    for (int off = 1; off < 16; off <<= 1) {
      int u = __shfl_up(is, off);
      if (tid >= off) is += u;
    }
    wpart[tid] = is;
  }
  __syncthreads();
  int wbase = (wv == 0) ? 0 : wpart[wv - 1];
  int total = wpart[15];
  int excl = wbase + inc - v;
  int gb = 0;
  if (v > 0) gb = atomicAdd(&bcnt[tid * CNT_STRIDE], v);
  __syncthreads();
  sc[tid] = excl;
  gofs[tid] = tid * CAP_C + gb - excl;
  __syncthreads();
#pragma unroll
  for (int r = 0; r < 4; ++r) {
    if (bb[r] >= 0)
      stage[sc[bb[r]] + pp[r]] = ((unsigned)bb[r] << 22) | (unsigned)ent[r];
  }
  __syncthreads();
  for (int i = tid; i < total; i += 1024) {
    unsigned pe = stage[i];
    int b = pe >> 22;
    int addr = gofs[b] + i;
    if (addr < b * CAP_C + CAP_C)
      buf[addr] = (int)(pe & 0x3FFFFFu);
  }
}

// Per-bucket dst-sort: buf entries -> u16 src lists + (beg,cnt) descriptors.
// Appends the self-loop src (= node id) at the end of each node's segment.
__global__ __launch_bounds__(512) void sortbuf(
    const int* __restrict__ bcnt, const int* __restrict__ buf,
    unsigned short* __restrict__ srcs16, int2* __restrict__ node_seg, int N) {
  __shared__ int hist[64];
  __shared__ int ofs[64];
  __shared__ unsigned short ents2[CAP_C + 64];
  int bucket = blockIdx.x;
  int tid = threadIdx.x;
  int lane = tid & 63;
  int cnt = min(bcnt[bucket * CNT_STRIDE], CAP_C - 64);  // room for 64 selfs
  if (tid < 64) hist[tid] = 0;
  __syncthreads();
  const int* __restrict__ bseg = buf + (size_t)bucket * CAP_C;
  int dv[6], rv[6], sv[6];
  bool hv[6];
#pragma unroll
  for (int r = 0; r < 6; ++r) {
    int i = tid + r * 512;
    hv[r] = i < cnt;
    dv[r] = 0; rv[r] = 0; sv[r] = 0;
    if (hv[r]) {
      int e = bseg[i];
      dv[r] = e & CB_MASK; sv[r] = e >> CB_SHIFT;
      rv[r] = atomicAdd(&hist[dv[r]], 1);
    }
  }
  __syncthreads();
  if (tid < 64) {  // exclusive scan over (hist + 1): one extra slot per node
    int v = hist[tid] + 1;
    int inc = v;
#pragma unroll
    for (int off = 1; off < 64; off <<= 1) {
      int u = __shfl_up(inc, off);
      if (lane >= off) inc += u;
    }
    ofs[tid] = inc - v;
  }
  __syncthreads();
#pragma unroll
  for (int r = 0; r < 6; ++r)
    if (hv[r]) ents2[ofs[dv[r]] + rv[r]] = (unsigned short)sv[r];
  if (tid < 64)  // self-loop entry at segment end
    ents2[ofs[tid] + hist[tid]] = (unsigned short)((bucket << CB_SHIFT) + tid);
  __syncthreads();
  int total = cnt + 64;
  unsigned short* __restrict__ oseg = srcs16 + (size_t)bucket * CAP_C;
  for (int i = tid; i < total; i += 512) oseg[i] = ents2[i];
  if (tid < 64) {
    int nn = (bucket << CB_SHIFT) + tid;
    if (nn < N)
      node_seg[nn] = make_int2(bucket * CAP_C + ofs[tid], hist[tid] + 1);
  }
}

// Fused layer-1: one wave per node; head-per-lane, 8 edges per pass,
// static 2x4-pass groups (4 gathers in flight), node_seg prefetch.
__global__ __launch_bounds__(256) void gather1w(
    const int2* __restrict__ node_seg, const unsigned short* __restrict__ srcs16,
    const uint4* __restrict__ xl16, const uint4* __restrict__ xr16,
    const float* __restrict__ att, const float* __restrict__ b1,
    const float* __restrict__ W2l, const float* __restrict__ W2r,
    float* __restrict__ hl, float* __restrict__ hr, int N, int nwaves) {
  int wid = blockIdx.x * 4 + (threadIdx.x >> 6);
  int lane = threadIdx.x & 63;
  int eslot = lane >> 3;   // edge slot within a pass (0..7)
  int h = lane & 7;        // head owned by this lane (all 8 channels)
  float4 atA = ((const float4*)att)[2 * h];
  float4 atB = ((const float4*)att)[2 * h + 1];
  h2 at0 = {(_Float16)(atA.x * LOG2E), (_Float16)(atA.y * LOG2E)};
  h2 at1 = {(_Float16)(atA.z * LOG2E), (_Float16)(atA.w * LOG2E)};
  h2 at2 = {(_Float16)(atB.x * LOG2E), (_Float16)(atB.y * LOG2E)};
  h2 at3 = {(_Float16)(atB.z * LOG2E), (_Float16)(atB.w * LOG2E)};
  const h2 slope = {(_Float16)NEG_SLOPE, (_Float16)NEG_SLOPE};

  if (wid >= N) return;
  int2 seg = node_seg[wid];
  for (int n = wid; n < N; n += nwaves) {
    int np = n + nwaves;
    int2 segN;
    if (np < N) segN = node_seg[np];  // prefetch next node's descriptor
    uint4 bvu = xr16[(size_t)n * 8 + h];
    h2 bv0 = __builtin_bit_cast(h2, bvu.x), bv1 = __builtin_bit_cast(h2, bvu.y);
    h2 bv2 = __builtin_bit_cast(h2, bvu.z), bv3 = __builtin_bit_cast(h2, bvu.w);
    float acc0 = 0.f, acc1 = 0.f, acc2 = 0.f, acc3 = 0.f;
    float acc4 = 0.f, acc5 = 0.f, acc6 = 0.f, acc7 = 0.f;
    float den = 0.f;
    int beg = seg.x, cnt = seg.y;  // cnt includes the appended self-loop
    for (int base = 0; base < cnt; base += 64) {
      int m = min(64, cnt - base);            // uniform
      int e = srcs16[beg + base + lane];      // coalesced u16 chunk (pad-safe)
#pragma unroll
      for (int g = 0; g < 2; ++g) {
        if (g * 32 >= m) break;               // uniform
        int s[4]; float live[4];
#pragma unroll
        for (int k = 0; k < 4; ++k) {
          int idx = ((g * 4 + k) * 8) | eslot;
          int idxc = min(idx, m - 1);
          s[k] = __shfl(e, idxc);
          live[k] = (idx < m) ? 1.f : 0.f;
        }
        uint4 au[4];
#pragma unroll
        for (int k = 0; k < 4; ++k)
          au[k] = xl16[(size_t)s[k] * 8 + h];  // 4 gathers in flight
#pragma unroll
        for (int k = 0; k < 4; ++k) {
          h2 a0 = __builtin_bit_cast(h2, au[k].x), a1 = __builtin_bit_cast(h2, au[k].y);
          h2 a2 = __builtin_bit_cast(h2, au[k].z), a3 = __builtin_bit_cast(h2, au[k].w);
          h2 t0 = lrelu_pk(a0 + bv0, slope), t1 = lrelu_pk(a1 + bv1, slope);
          h2 t2 = lrelu_pk(a2 + bv2, slope), t3 = lrelu_pk(a3 + bv3, slope);
          float p = __builtin_amdgcn_fdot2(t3, at3,
                    __builtin_amdgcn_fdot2(t2, at2,
                    __builtin_amdgcn_fdot2(t1, at1,
                    __builtin_amdgcn_fdot2(t0, at0, 0.f, false), false), false), false);
          float w = EXP2(p) * live[k];
          den += w;
          acc0 = fmaf(w, (float)a0.x, acc0); acc1 = fmaf(w, (float)a0.y, acc1);
          acc2 = fmaf(w, (float)a1.x, acc2); acc3 = fmaf(w, (float)a1.y, acc3);
          acc4 = fmaf(w, (float)a2.x, acc4); acc5 = fmaf(w, (float)a2.y, acc5);
          acc6 = fmaf(w, (float)a3.x, acc6); acc7 = fmaf(w, (float)a3.y, acc7);
        }
      }
    }
    // combine across the 8 edge-slots (lanes differing in bits 3..5)
#pragma unroll
    for (int o = 8; o < 64; o <<= 1) {
      acc0 += __shfl_xor(acc0, o); acc1 += __shfl_xor(acc1, o);
      acc2 += __shfl_xor(acc2, o); acc3 += __shfl_xor(acc3, o);
      acc4 += __shfl_xor(acc4, o); acc5 += __shfl_xor(acc5, o);
      acc6 += __shfl_xor(acc6, o); acc7 += __shfl_xor(acc7, o);
      den  += __shfl_xor(den, o);
    }
    // finalize: normalize, +b1, ELU, project to layer-2 scalars
    float inv = 1.f / den;
    float4 b1A = ((const float4*)b1)[2 * h], b1B = ((const float4*)b1)[2 * h + 1];
    float v0 = acc0 * inv + b1A.x, v1 = acc1 * inv + b1A.y;
    float v2 = acc2 * inv + b1A.z, v3 = acc3 * inv + b1A.w;
    float v4 = acc4 * inv + b1B.x, v5 = acc5 * inv + b1B.y;
    float v6 = acc6 * inv + b1B.z, v7 = acc7 * inv + b1B.w;
    float e0 = v0 > 0.f ? v0 : (__expf(v0) - 1.f);
    float e1 = v1 > 0.f ? v1 : (__expf(v1) - 1.f);
    float e2 = v2 > 0.f ? v2 : (__expf(v2) - 1.f);
    float e3 = v3 > 0.f ? v3 : (__expf(v3) - 1.f);
    float e4 = v4 > 0.f ? v4 : (__expf(v4) - 1.f);
    float e5 = v5 > 0.f ? v5 : (__expf(v5) - 1.f);
    float e6 = v6 > 0.f ? v6 : (__expf(v6) - 1.f);
    float e7 = v7 > 0.f ? v7 : (__expf(v7) - 1.f);
    float4 wlA = ((const float4*)W2l)[2 * h], wlB = ((const float4*)W2l)[2 * h + 1];
    float4 wrA = ((const float4*)W2r)[2 * h], wrB = ((const float4*)W2r)[2 * h + 1];
    float pl = e0 * wlA.x + e1 * wlA.y + e2 * wlA.z + e3 * wlA.w +
               e4 * wlB.x + e5 * wlB.y + e6 * wlB.z + e7 * wlB.w;
    float pr = e0 * wrA.x + e1 * wrA.y + e2 * wrA.z + e3 * wrA.w +
               e4 * wrB.x + e5 * wrB.y + e6 * wrB.z + e7 * wrB.w;
#pragma unroll
    for (int o = 1; o < 8; o <<= 1) {  // reduce across heads (lanes 0..7)
      pl += __shfl_xor(pl, o);
      pr += __shfl_xor(pr, o);
    }
    if (lane == 0) { hl[n] = pl; hr[n] = pr; }
    seg = segN;
  }
}

// Layer-2: one wave per node; lanes stride the segment (self included).
__global__ __launch_bounds__(256) void gather2w(
    const int2* __restrict__ node_seg, const unsigned short* __restrict__ srcs16,
    const float* __restrict__ hl, const float* __restrict__ hr,
    const float* __restrict__ att2, const float* __restrict__ b2,
    float* __restrict__ out, int N, int nwaves) {
  int wid = blockIdx.x * 4 + (threadIdx.x >> 6);
  int lane = threadIdx.x & 63;
  float a2 = att2[0] * LOG2E;
  float b2v = b2[0];
  for (int n = wid; n < N; n += nwaves) {
    int2 seg = node_seg[n];
    float hrd = hr[n];
    float num = 0.f, den = 0.f;
    for (int j = lane; j < seg.y; j += 64) {
      int s = srcs16[seg.x + j];
      float hls = hl[s];
      float t = hls + hrd;
      t = fmaxf(t, NEG_SLOPE * t);
      float wgt = EXP2(t * a2);
      num = fmaf(wgt, hls, num);
      den += wgt;
    }
#pragma unroll
    for (int off = 1; off < 64; off <<= 1) {
      num += __shfl_xor(num, off);
      den += __shfl_xor(den, off);
    }
    if (lane == 0) out[n] = num / den + b2v;
  }
}

extern "C" void kernel_launch(void* const* d_in, const int* in_sizes, int n_in,
                              void* d_out, int out_size, void* d_ws, size_t ws_size,
                              hipStream_t stream) {
  const float* x    = (const float*)d_in[0];
  const int*   ei   = (const int*)d_in[1];
  const float* W1l  = (const float*)d_in[2];
  const float* W1r  = (const float*)d_in[3];
  const float* att1 = (const float*)d_in[4];
  const float* b1   = (const float*)d_in[5];
  const float* W2l  = (const float*)d_in[6];
  const float* W2r  = (const float*)d_in[7];
  const float* att2 = (const float*)d_in[8];
  const float* b2   = (const float*)d_in[9];
  float* out = (float*)d_out;

  const int N  = in_sizes[0] / 128;          // 50000
  const int E0 = in_sizes[1] / 2;            // 1600000
  const int NB = (N + CB_MASK) >> CB_SHIFT;  // 782 buckets of 64 nodes

  // workspace layout
  float* ws  = (float*)d_ws;
  __half* xlh = (__half*)ws;                 // N*64 halves (N*32 floats)
  __half* xrh = (__half*)(ws + (size_t)N * 32);  // N*64 halves
  float* hl  = ws + (size_t)N * 64;          // N
  float* hr  = hl + N;                       // N
  int2* node_seg = (int2*)(hr + N);          // N int2
  int* bcnt  = (int*)(node_seg + N);             // NB*CNT_STRIDE (zeroed by gemm tail)
  int* buf   = bcnt + (size_t)NB * CNT_STRIDE;   // NB*CAP_C ints
  unsigned short* srcs16 = (unsigned short*)(buf + (size_t)NB * CAP_C);
  // srcs16: NB*CAP_C u16 + 64 pad entries

  const int GEMM_HALF = 512;
  const int ZB = 16;  // zeroing blocks for bcnt (NB*CNT_STRIDE ints)
  gemm_reg_dual<<<GEMM_HALF * 2 + ZB, 256, 0, stream>>>(
      x, W1l, W1r, xlh, xrh, N, GEMM_HALF, bcnt, NB * CNT_STRIDE);
  bucket_scatter<<<(E0 + CHUNK - 1) / CHUNK, 1024, 0, stream>>>(ei, E0, bcnt, buf);
  sortbuf<<<NB, 512, 0, stream>>>(bcnt, buf, srcs16, node_seg, N);
  const int GBLK = 2048;  // 8 blocks/CU
  gather1w<<<GBLK, 256, 0, stream>>>(node_seg, srcs16, (const uint4*)xlh,
                                     (const uint4*)xrh, att1, b1, W2l, W2r,
                                     hl, hr, N, GBLK * 4);
  gather2w<<<GBLK, 256, 0, stream>>>(node_seg, srcs16, hl, hr, att2, b2,
                                     out, N, GBLK * 4);
}

// Round 21
// 127.654 us; speedup vs baseline: 1.0492x; 1.0492x over previous
//
#include <hip/hip_runtime.h>
#include <hip/hip_fp16.h>

// ---------------------------------------------------------------------------
// GATv2 (2 layers): scatter -> per-bucket dst-sort -> wave-per-node gathers.
// Bucket = dst >> 6 (64 nodes/bucket, 782 buckets).
//  1) bucket_scatter: block counting sort -> bucket-grouped global buf.
//     CHUNK=8192 (R20 lesson: CHUNK=4096 doubled per-block fixed cost +
//     write-piece line amplification; scatter is NOT fill-bound).
//  2) sortbuf: per bucket, sort entries by dst, write u16 src lists +
//     per-node (beg,cnt) descriptors. SELF-LOOP APPENDED to each node's
//     segment (scan over hist+1) -- gathers have no separate self pass.
//  3) gather1w: ONE WAVE PER NODE, head-per-lane (lane = eslot*8+h; lane
//     holds all 8 fp16 channels of head h as uint4; 8 edges per pass,
//     one coalesced u16 chunk per 64 edges + shfl broadcast of ids).
//     Inner loop = STATIC 2x4-pass groups: 4 gathers issued back-to-back
//     (R18: dynamic predication broke load clustering; R16: scalar
//     broadcast loads serialize VMEM latency). Grid 4096 blocks (2x
//     oversubscribed): block refill smooths the 6-vs-7-nodes/wave
//     quantization tail (R21).
//     f16 math via __builtin_elementwise_* (R15: scalar selects -> 4x fat).
//  4) gather2w: one wave per node, scalar layer-2 features (self in list).
// bcnt zeroing folded into the gemm launch (tail blocks) -- no memset.
// No fp atomics in hot paths (R8/R9). Softmax without max-subtraction
// (scores O(10), fp32-safe; shift-invariant).
// ---------------------------------------------------------------------------

#define NEG_SLOPE 0.2f
#define LOG2E 1.4426950408889634f
#define CB_SHIFT 6
#define CB_MASK 63
#define CAP_C 3072     // mean 2048/bucket; clamp to CAP_C-64 to fit selfs
#define CHUNK 8192     // edges per scatter block (8 per thread)
#define CNT_STRIDE 32  // one counter per 128B

#if __has_builtin(__builtin_amdgcn_exp2f)
#define EXP2(x) __builtin_amdgcn_exp2f(x)
#else
#define EXP2(x) __expf((x)*0.6931471805599453f)
#endif

typedef _Float16 h2 __attribute__((ext_vector_type(2)));

__device__ __forceinline__ h2 lrelu_pk(h2 t, h2 slope) {
  return __builtin_elementwise_max(t, t * slope);  // v_pk_mul + v_pk_max
}

// Dual GEMM, split grid: blocks [0,half) -> xlh, [half,2*half) -> xrh (fp16).
// Blocks [2*half, 2*half+ZB) zero bcnt (replaces hipMemsetAsync launch).
__global__ __launch_bounds__(256) void gemm_reg_dual(
    const float* __restrict__ x, const float* __restrict__ Wl,
    const float* __restrict__ Wr, __half* __restrict__ xlh,
    __half* __restrict__ xrh, int N, int half_blocks,
    int* __restrict__ bcnt, int bcnt_n) {
  if ((int)blockIdx.x >= 2 * half_blocks) {
    int zb = blockIdx.x - 2 * half_blocks;
    for (int i = zb * 256 + threadIdx.x; i < bcnt_n; i += 256 * 16)
      bcnt[i] = 0;
    return;
  }
  bool second = blockIdx.x >= half_blocks;
  int bid = second ? blockIdx.x - half_blocks : blockIdx.x;
  const float* __restrict__ W = second ? Wr : Wl;
  __half* __restrict__ dst = second ? xrh : xlh;
  int nwaves = half_blocks * 4;
  int wid = bid * 4 + (threadIdx.x >> 6);
  int j = threadIdx.x & 63;
  float Wcol[128];
#pragma unroll
  for (int k = 0; k < 128; ++k) Wcol[k] = W[k * 64 + j];  // coalesced, L2-hot
  for (int n = wid; n < N; n += nwaves) {
    const float2 xv2 = *(const float2*)&x[(size_t)n * 128 + 2 * j];
    float xa = xv2.x, xb = xv2.y;
    float acc0 = 0.f, acc1 = 0.f;
#pragma unroll
    for (int k = 0; k < 128; k += 2) {
      unsigned b0 = __builtin_amdgcn_readlane(__float_as_uint(xa), k >> 1);
      unsigned b1 = __builtin_amdgcn_readlane(__float_as_uint(xb), k >> 1);
      acc0 = fmaf(__uint_as_float(b0), Wcol[k], acc0);
      acc1 = fmaf(__uint_as_float(b1), Wcol[k + 1], acc1);
    }
    dst[(size_t)n * 64 + j] = __float2half(acc0 + acc1);
  }
}

// Block-level counting-sort scatter: CHUNK edges -> bucket-grouped global buf.
__global__ __launch_bounds__(1024) void bucket_scatter(
    const int* __restrict__ ei, int E0, int* __restrict__ bcnt,
    int* __restrict__ buf) {
  __shared__ int hist[1024];
  __shared__ int sc[1024];
  __shared__ int gofs[1024];
  __shared__ int wpart[16];
  __shared__ unsigned stage[CHUNK];
  int tid = threadIdx.x;
  int lane = tid & 63, wv = tid >> 6;
  int base = blockIdx.x * CHUNK;
  hist[tid] = 0;
  __syncthreads();
  int bb[8], pp[8], ent[8];
#pragma unroll
  for (int r = 0; r < 8; ++r) {
    int e = base + r * 1024 + tid;
    if (e < E0) {
      int s = ei[e], d = ei[E0 + e];
      int b = d >> CB_SHIFT;
      bb[r] = b;
      ent[r] = (s << CB_SHIFT) | (d & CB_MASK);
      pp[r] = atomicAdd(&hist[b], 1);
    } else {
      bb[r] = -1;
    }
  }
  __syncthreads();
  int v = hist[tid];
  int inc = v;
#pragma unroll
  for (int off = 1; off < 64; off <<= 1) {
    int u = __shfl_up(inc, off);
    if (lane >= off) inc += u;
  }
  if (lane == 63) wpart[wv] = inc;
  __syncthreads();
  if (tid < 16) {
    int is = wpart[tid];
#pragma unroll
    for (int off = 1; off < 16; off <<= 1) {
      int u = __shfl_up(is, off);
      if (tid >= off) is += u;
    }
    wpart[tid] = is;
  }
  __syncthreads();
  int wbase = (wv == 0) ? 0 : wpart[wv - 1];
  int total = wpart[15];
  int excl = wbase + inc - v;
  int gb = 0;
  if (v > 0) gb = atomicAdd(&bcnt[tid * CNT_STRIDE], v);
  __syncthreads();
  sc[tid] = excl;
  gofs[tid] = tid * CAP_C + gb - excl;
  __syncthreads();
#pragma unroll
  for (int r = 0; r < 8; ++r) {
    if (bb[r] >= 0)
      stage[sc[bb[r]] + pp[r]] = ((unsigned)bb[r] << 22) | (unsigned)ent[r];
  }
  __syncthreads();
  for (int i = tid; i < total; i += 1024) {
    unsigned pe = stage[i];
    int b = pe >> 22;
    int addr = gofs[b] + i;
    if (addr < b * CAP_C + CAP_C)
      buf[addr] = (int)(pe & 0x3FFFFFu);
  }
}

// Per-bucket dst-sort: buf entries -> u16 src lists + (beg,cnt) descriptors.
// Appends the self-loop src (= node id) at the end of each node's segment.
__global__ __launch_bounds__(512) void sortbuf(
    const int* __restrict__ bcnt, const int* __restrict__ buf,
    unsigned short* __restrict__ srcs16, int2* __restrict__ node_seg, int N) {
  __shared__ int hist[64];
  __shared__ int ofs[64];
  __shared__ unsigned short ents2[CAP_C + 64];
  int bucket = blockIdx.x;
  int tid = threadIdx.x;
  int lane = tid & 63;
  int cnt = min(bcnt[bucket * CNT_STRIDE], CAP_C - 64);  // room for 64 selfs
  if (tid < 64) hist[tid] = 0;
  __syncthreads();
  const int* __restrict__ bseg = buf + (size_t)bucket * CAP_C;
  int dv[6], rv[6], sv[6];
  bool hv[6];
#pragma unroll
  for (int r = 0; r < 6; ++r) {
    int i = tid + r * 512;
    hv[r] = i < cnt;
    dv[r] = 0; rv[r] = 0; sv[r] = 0;
    if (hv[r]) {
      int e = bseg[i];
      dv[r] = e & CB_MASK; sv[r] = e >> CB_SHIFT;
      rv[r] = atomicAdd(&hist[dv[r]], 1);
    }
  }
  __syncthreads();
  if (tid < 64) {  // exclusive scan over (hist + 1): one extra slot per node
    int v = hist[tid] + 1;
    int inc = v;
#pragma unroll
    for (int off = 1; off < 64; off <<= 1) {
      int u = __shfl_up(inc, off);
      if (lane >= off) inc += u;
    }
    ofs[tid] = inc - v;
  }
  __syncthreads();
#pragma unroll
  for (int r = 0; r < 6; ++r)
    if (hv[r]) ents2[ofs[dv[r]] + rv[r]] = (unsigned short)sv[r];
  if (tid < 64)  // self-loop entry at segment end
    ents2[ofs[tid] + hist[tid]] = (unsigned short)((bucket << CB_SHIFT) + tid);
  __syncthreads();
  int total = cnt + 64;
  unsigned short* __restrict__ oseg = srcs16 + (size_t)bucket * CAP_C;
  for (int i = tid; i < total; i += 512) oseg[i] = ents2[i];
  if (tid < 64) {
    int nn = (bucket << CB_SHIFT) + tid;
    if (nn < N)
      node_seg[nn] = make_int2(bucket * CAP_C + ofs[tid], hist[tid] + 1);
  }
}

// Fused layer-1: one wave per node; head-per-lane, 8 edges per pass,
// static 2x4-pass groups (4 gathers in flight), node_seg prefetch.
__global__ __launch_bounds__(256) void gather1w(
    const int2* __restrict__ node_seg, const unsigned short* __restrict__ srcs16,
    const uint4* __restrict__ xl16, const uint4* __restrict__ xr16,
    const float* __restrict__ att, const float* __restrict__ b1,
    const float* __restrict__ W2l, const float* __restrict__ W2r,
    float* __restrict__ hl, float* __restrict__ hr, int N, int nwaves) {
  int wid = blockIdx.x * 4 + (threadIdx.x >> 6);
  int lane = threadIdx.x & 63;
  int eslot = lane >> 3;   // edge slot within a pass (0..7)
  int h = lane & 7;        // head owned by this lane (all 8 channels)
  float4 atA = ((const float4*)att)[2 * h];
  float4 atB = ((const float4*)att)[2 * h + 1];
  h2 at0 = {(_Float16)(atA.x * LOG2E), (_Float16)(atA.y * LOG2E)};
  h2 at1 = {(_Float16)(atA.z * LOG2E), (_Float16)(atA.w * LOG2E)};
  h2 at2 = {(_Float16)(atB.x * LOG2E), (_Float16)(atB.y * LOG2E)};
  h2 at3 = {(_Float16)(atB.z * LOG2E), (_Float16)(atB.w * LOG2E)};
  const h2 slope = {(_Float16)NEG_SLOPE, (_Float16)NEG_SLOPE};

  if (wid >= N) return;
  int2 seg = node_seg[wid];
  for (int n = wid; n < N; n += nwaves) {
    int np = n + nwaves;
    int2 segN;
    if (np < N) segN = node_seg[np];  // prefetch next node's descriptor
    uint4 bvu = xr16[(size_t)n * 8 + h];
    h2 bv0 = __builtin_bit_cast(h2, bvu.x), bv1 = __builtin_bit_cast(h2, bvu.y);
    h2 bv2 = __builtin_bit_cast(h2, bvu.z), bv3 = __builtin_bit_cast(h2, bvu.w);
    float acc0 = 0.f, acc1 = 0.f, acc2 = 0.f, acc3 = 0.f;
    float acc4 = 0.f, acc5 = 0.f, acc6 = 0.f, acc7 = 0.f;
    float den = 0.f;
    int beg = seg.x, cnt = seg.y;  // cnt includes the appended self-loop
    for (int base = 0; base < cnt; base += 64) {
      int m = min(64, cnt - base);            // uniform
      int e = srcs16[beg + base + lane];      // coalesced u16 chunk (pad-safe)
#pragma unroll
      for (int g = 0; g < 2; ++g) {
        if (g * 32 >= m) break;               // uniform
        int s[4]; float live[4];
#pragma unroll
        for (int k = 0; k < 4; ++k) {
          int idx = ((g * 4 + k) * 8) | eslot;
          int idxc = min(idx, m - 1);
          s[k] = __shfl(e, idxc);
          live[k] = (idx < m) ? 1.f : 0.f;
        }
        uint4 au[4];
#pragma unroll
        for (int k = 0; k < 4; ++k)
          au[k] = xl16[(size_t)s[k] * 8 + h];  // 4 gathers in flight
#pragma unroll
        for (int k = 0; k < 4; ++k) {
          h2 a0 = __builtin_bit_cast(h2, au[k].x), a1 = __builtin_bit_cast(h2, au[k].y);
          h2 a2 = __builtin_bit_cast(h2, au[k].z), a3 = __builtin_bit_cast(h2, au[k].w);
          h2 t0 = lrelu_pk(a0 + bv0, slope), t1 = lrelu_pk(a1 + bv1, slope);
          h2 t2 = lrelu_pk(a2 + bv2, slope), t3 = lrelu_pk(a3 + bv3, slope);
          float p = __builtin_amdgcn_fdot2(t3, at3,
                    __builtin_amdgcn_fdot2(t2, at2,
                    __builtin_amdgcn_fdot2(t1, at1,
                    __builtin_amdgcn_fdot2(t0, at0, 0.f, false), false), false), false);
          float w = EXP2(p) * live[k];
          den += w;
          acc0 = fmaf(w, (float)a0.x, acc0); acc1 = fmaf(w, (float)a0.y, acc1);
          acc2 = fmaf(w, (float)a1.x, acc2); acc3 = fmaf(w, (float)a1.y, acc3);
          acc4 = fmaf(w, (float)a2.x, acc4); acc5 = fmaf(w, (float)a2.y, acc5);
          acc6 = fmaf(w, (float)a3.x, acc6); acc7 = fmaf(w, (float)a3.y, acc7);
        }
      }
    }
    // combine across the 8 edge-slots (lanes differing in bits 3..5)
#pragma unroll
    for (int o = 8; o < 64; o <<= 1) {
      acc0 += __shfl_xor(acc0, o); acc1 += __shfl_xor(acc1, o);
      acc2 += __shfl_xor(acc2, o); acc3 += __shfl_xor(acc3, o);
      acc4 += __shfl_xor(acc4, o); acc5 += __shfl_xor(acc5, o);
      acc6 += __shfl_xor(acc6, o); acc7 += __shfl_xor(acc7, o);
      den  += __shfl_xor(den, o);
    }
    // finalize: normalize, +b1, ELU, project to layer-2 scalars
    float inv = 1.f / den;
    float4 b1A = ((const float4*)b1)[2 * h], b1B = ((const float4*)b1)[2 * h + 1];
    float v0 = acc0 * inv + b1A.x, v1 = acc1 * inv + b1A.y;
    float v2 = acc2 * inv + b1A.z, v3 = acc3 * inv + b1A.w;
    float v4 = acc4 * inv + b1B.x, v5 = acc5 * inv + b1B.y;
    float v6 = acc6 * inv + b1B.z, v7 = acc7 * inv + b1B.w;
    float e0 = v0 > 0.f ? v0 : (__expf(v0) - 1.f);
    float e1 = v1 > 0.f ? v1 : (__expf(v1) - 1.f);
    float e2 = v2 > 0.f ? v2 : (__expf(v2) - 1.f);
    float e3 = v3 > 0.f ? v3 : (__expf(v3) - 1.f);
    float e4 = v4 > 0.f ? v4 : (__expf(v4) - 1.f);
    float e5 = v5 > 0.f ? v5 : (__expf(v5) - 1.f);
    float e6 = v6 > 0.f ? v6 : (__expf(v6) - 1.f);
    float e7 = v7 > 0.f ? v7 : (__expf(v7) - 1.f);
    float4 wlA = ((const float4*)W2l)[2 * h], wlB = ((const float4*)W2l)[2 * h + 1];
    float4 wrA = ((const float4*)W2r)[2 * h], wrB = ((const float4*)W2r)[2 * h + 1];
    float pl = e0 * wlA.x + e1 * wlA.y + e2 * wlA.z + e3 * wlA.w +
               e4 * wlB.x + e5 * wlB.y + e6 * wlB.z + e7 * wlB.w;
    float pr = e0 * wrA.x + e1 * wrA.y + e2 * wrA.z + e3 * wrA.w +
               e4 * wrB.x + e5 * wrB.y + e6 * wrB.z + e7 * wrB.w;
#pragma unroll
    for (int o = 1; o < 8; o <<= 1) {  // reduce across heads (lanes 0..7)
      pl += __shfl_xor(pl, o);
      pr += __shfl_xor(pr, o);
    }
    if (lane == 0) { hl[n] = pl; hr[n] = pr; }
    seg = segN;
  }
}

// Layer-2: one wave per node; lanes stride the segment (self included).
__global__ __launch_bounds__(256) void gather2w(
    const int2* __restrict__ node_seg, const unsigned short* __restrict__ srcs16,
    const float* __restrict__ hl, const float* __restrict__ hr,
    const float* __restrict__ att2, const float* __restrict__ b2,
    float* __restrict__ out, int N, int nwaves) {
  int wid = blockIdx.x * 4 + (threadIdx.x >> 6);
  int lane = threadIdx.x & 63;
  float a2 = att2[0] * LOG2E;
  float b2v = b2[0];
  for (int n = wid; n < N; n += nwaves) {
    int2 seg = node_seg[n];
    float hrd = hr[n];
    float num = 0.f, den = 0.f;
    for (int j = lane; j < seg.y; j += 64) {
      int s = srcs16[seg.x + j];
      float hls = hl[s];
      float t = hls + hrd;
      t = fmaxf(t, NEG_SLOPE * t);
      float wgt = EXP2(t * a2);
      num = fmaf(wgt, hls, num);
      den += wgt;
    }
#pragma unroll
    for (int off = 1; off < 64; off <<= 1) {
      num += __shfl_xor(num, off);
      den += __shfl_xor(den, off);
    }
    if (lane == 0) out[n] = num / den + b2v;
  }
}

extern "C" void kernel_launch(void* const* d_in, const int* in_sizes, int n_in,
                              void* d_out, int out_size, void* d_ws, size_t ws_size,
                              hipStream_t stream) {
  const float* x    = (const float*)d_in[0];
  const int*   ei   = (const int*)d_in[1];
  const float* W1l  = (const float*)d_in[2];
  const float* W1r  = (const float*)d_in[3];
  const float* att1 = (const float*)d_in[4];
  const float* b1   = (const float*)d_in[5];
  const float* W2l  = (const float*)d_in[6];
  const float* W2r  = (const float*)d_in[7];
  const float* att2 = (const float*)d_in[8];
  const float* b2   = (const float*)d_in[9];
  float* out = (float*)d_out;

  const int N  = in_sizes[0] / 128;          // 50000
  const int E0 = in_sizes[1] / 2;            // 1600000
  const int NB = (N + CB_MASK) >> CB_SHIFT;  // 782 buckets of 64 nodes

  // workspace layout
  float* ws  = (float*)d_ws;
  __half* xlh = (__half*)ws;                 // N*64 halves (N*32 floats)
  __half* xrh = (__half*)(ws + (size_t)N * 32);  // N*64 halves
  float* hl  = ws + (size_t)N * 64;          // N
  float* hr  = hl + N;                       // N
  int2* node_seg = (int2*)(hr + N);          // N int2
  int* bcnt  = (int*)(node_seg + N);             // NB*CNT_STRIDE (zeroed by gemm tail)
  int* buf   = bcnt + (size_t)NB * CNT_STRIDE;   // NB*CAP_C ints
  unsigned short* srcs16 = (unsigned short*)(buf + (size_t)NB * CAP_C);
  // srcs16: NB*CAP_C u16 + 64 pad entries

  const int GEMM_HALF = 512;
  const int ZB = 16;  // zeroing blocks for bcnt (NB*CNT_STRIDE ints)
  gemm_reg_dual<<<GEMM_HALF * 2 + ZB, 256, 0, stream>>>(
      x, W1l, W1r, xlh, xrh, N, GEMM_HALF, bcnt, NB * CNT_STRIDE);
  bucket_scatter<<<(E0 + CHUNK - 1) / CHUNK, 1024, 0, stream>>>(ei, E0, bcnt, buf);
  sortbuf<<<NB, 512, 0, stream>>>(bcnt, buf, srcs16, node_seg, N);
  const int GBLK = 4096;  // 2x oversubscribed: refill smooths the node tail
  gather1w<<<GBLK, 256, 0, stream>>>(node_seg, srcs16, (const uint4*)xlh,
                                     (const uint4*)xrh, att1, b1, W2l, W2r,
                                     hl, hr, N, GBLK * 4);
  gather2w<<<GBLK, 256, 0, stream>>>(node_seg, srcs16, hl, hr, att2, b2,
                                     out, N, GBLK * 4);
}